// Round 1
// baseline (96.396 us; speedup 1.0000x reference)
//
#include <hip/hip_runtime.h>

// SVF: linear time-varying 2-state recurrence, parallelized as an
// associative scan over affine maps (A, b):  s_t = A_t s_{t-1} + b_t,
//   A_t = 2*H_t - I,  b_t = 2*g*T*x*[1, g],  Y_t = (s_t + s_{t-1})/2.
// Decomposition: 64 rows x 16 chunks = 1024 blocks, 256 thr/block,
// 8 sequential timesteps per thread.

#define BATCH     64
#define SEQ       32768
#define CHUNKS    16
#define CHUNK_LEN (SEQ / CHUNKS)    // 2048
#define TPB       256
#define STEPS     (CHUNK_LEN / TPB) // 8
#define NBLK      (BATCH * CHUNKS)  // 1024

struct Aff { float a00, a01, a10, a11, b0, b1; };

// Apply 'e' (earlier) first, then 'l' (later).
__device__ __forceinline__ Aff compose(const Aff l, const Aff e) {
    Aff r;
    r.a00 = fmaf(l.a00, e.a00, l.a01 * e.a10);
    r.a01 = fmaf(l.a00, e.a01, l.a01 * e.a11);
    r.a10 = fmaf(l.a10, e.a00, l.a11 * e.a10);
    r.a11 = fmaf(l.a10, e.a01, l.a11 * e.a11);
    r.b0  = fmaf(l.a00, e.b0, fmaf(l.a01, e.b1, l.b0));
    r.b1  = fmaf(l.a10, e.b0, fmaf(l.a11, e.b1, l.b1));
    return r;
}

__device__ __forceinline__ Aff step_affine(float gi, float Ri, float xi) {
    float T  = 1.0f / fmaf(gi, gi + Ri, 1.0f);   // 1/(1+g*(g+2R))
    float Tg = T * gi;
    Aff r;
    r.a00 = 2.0f * T - 1.0f;
    r.a01 = -2.0f * Tg;
    r.a10 = 2.0f * Tg;
    r.a11 = 2.0f * fmaf(Tg, Ri, T) - 1.0f;       // 2*T*(2R*g+1)-1
    r.b0  = 2.0f * Tg * xi;
    r.b1  = gi * r.b0;
    return r;
}

// Order-preserving inclusive Hillis-Steele scan over the block (time order =
// thread order). Double-buffered: 1 barrier per level, 8 levels.
__device__ __forceinline__ Aff block_scan_incl(Aff v, Aff (*buf)[TPB], int t) {
    int src = 0;
    buf[0][t] = v;
    __syncthreads();
#pragma unroll
    for (int off = 1; off < TPB; off <<= 1) {
        Aff cur = buf[src][t];
        int idx = (t >= off) ? (t - off) : 0;    // clamped: safe speculative read
        Aff prev = buf[src][idx];
        Aff res = (t >= off) ? compose(cur, prev) : cur;
        buf[1 - src][t] = res;
        src ^= 1;
        __syncthreads();
    }
    return buf[src][t];
}

__device__ __forceinline__ void load8(const float* __restrict__ p, int base, float v[8]) {
    float4 a = *reinterpret_cast<const float4*>(p + base);
    float4 b = *reinterpret_cast<const float4*>(p + base + 4);
    v[0]=a.x; v[1]=a.y; v[2]=a.z; v[3]=a.w; v[4]=b.x; v[5]=b.y; v[6]=b.z; v[7]=b.w;
}

__global__ __launch_bounds__(TPB) void svf_chunk_reduce(
    const float* __restrict__ audio, const float* __restrict__ g,
    const float* __restrict__ twoR, Aff* __restrict__ chunk_comp)
{
    __shared__ Aff buf[2][TPB];
    const int t    = threadIdx.x;
    const int base = blockIdx.x * CHUNK_LEN + t * STEPS;

    float gv[STEPS], rv[STEPS], xv[STEPS];
    load8(g, base, gv); load8(twoR, base, rv); load8(audio, base, xv);

    Aff acc = step_affine(gv[0], rv[0], xv[0]);
#pragma unroll
    for (int i = 1; i < STEPS; ++i)
        acc = compose(step_affine(gv[i], rv[i], xv[i]), acc);

    Aff tot = block_scan_incl(acc, buf, t);
    if (t == TPB - 1) chunk_comp[blockIdx.x] = tot;   // whole-chunk affine
}

__global__ __launch_bounds__(TPB) void svf_emit(
    const float* __restrict__ audio, const float* __restrict__ g,
    const float* __restrict__ twoR, const float* __restrict__ mix,
    const Aff* __restrict__ chunk_comp, float* __restrict__ out)
{
    __shared__ Aff buf[2][TPB];
    const int blk  = blockIdx.x;
    const int b    = blk / CHUNKS;
    const int t    = threadIdx.x;
    const int base = blk * CHUNK_LEN + t * STEPS;

    float gv[STEPS], rv[STEPS], xv[STEPS];
    load8(g, base, gv); load8(twoR, base, rv); load8(audio, base, xv);

    Aff acc = step_affine(gv[0], rv[0], xv[0]);
#pragma unroll
    for (int i = 1; i < STEPS; ++i)
        acc = compose(step_affine(gv[i], rv[i], xv[i]), acc);

    Aff incl = block_scan_incl(acc, buf, t);
    // Each thread only touched its own slot after the scan's final barrier,
    // so re-stashing to buf[0][t] races with nobody.
    buf[0][t] = incl;
    __syncthreads();

    // Chunk start state: apply chunk affines 0..c-1 (uniform -> scalar loads).
    float cs0 = 1.0f, cs1 = 1.0f;  // s0 = ones(2)
    for (int cc = b * CHUNKS; cc < blk; ++cc) {
        Aff a = chunk_comp[cc];
        float n0 = fmaf(a.a00, cs0, fmaf(a.a01, cs1, a.b0));
        float n1 = fmaf(a.a10, cs0, fmaf(a.a11, cs1, a.b1));
        cs0 = n0; cs1 = n1;
    }

    // Thread segment start state = exclusive prefix applied to chunk start.
    float s0, s1;
    if (t == 0) { s0 = cs0; s1 = cs1; }
    else {
        Aff p = buf[0][t - 1];
        s0 = fmaf(p.a00, cs0, fmaf(p.a01, cs1, p.b0));
        s1 = fmaf(p.a10, cs0, fmaf(p.a11, cs1, p.b1));
    }

    // mix: [B,N,3] -> 24 consecutive floats per thread, 16B-aligned (96B/thread).
    const float4* m4 = reinterpret_cast<const float4*>(mix + 3 * base);
    float mv[24];
#pragma unroll
    for (int q = 0; q < 6; ++q) {
        float4 m = m4[q];
        mv[4*q+0]=m.x; mv[4*q+1]=m.y; mv[4*q+2]=m.z; mv[4*q+3]=m.w;
    }

    float ov[STEPS];
#pragma unroll
    for (int i = 0; i < STEPS; ++i) {
        float gi = gv[i], Ri = rv[i], xi = xv[i];
        float T  = 1.0f / fmaf(gi, gi + Ri, 1.0f);
        float w  = fmaf(gi, xi, s0);                       // g*x + s0
        float Y0 = T * fmaf(-gi, s1, w);                   // bp
        float Y1 = T * fmaf(gi, w, fmaf(Ri, gi, 1.0f) * s1); // lp
        float hp = xi - Ri * Y0 - Y1;
        ov[i] = fmaf(Ri * mv[3*i], Y0, fmaf(mv[3*i+1], Y1, mv[3*i+2] * hp));
        s0 = fmaf(2.0f, Y0, -s0);
        s1 = fmaf(2.0f, Y1, -s1);
    }

    *reinterpret_cast<float4*>(out + base)     = make_float4(ov[0], ov[1], ov[2], ov[3]);
    *reinterpret_cast<float4*>(out + base + 4) = make_float4(ov[4], ov[5], ov[6], ov[7]);
}

extern "C" void kernel_launch(void* const* d_in, const int* in_sizes, int n_in,
                              void* d_out, int out_size, void* d_ws, size_t ws_size,
                              hipStream_t stream) {
    const float* audio = (const float*)d_in[0];
    const float* g     = (const float*)d_in[1];
    const float* twoR  = (const float*)d_in[2];
    const float* mix   = (const float*)d_in[3];
    float* out = (float*)d_out;
    Aff* chunk_comp = (Aff*)d_ws;   // 1024 * 24 B = 24 KB

    svf_chunk_reduce<<<NBLK, TPB, 0, stream>>>(audio, g, twoR, chunk_comp);
    svf_emit<<<NBLK, TPB, 0, stream>>>(audio, g, twoR, mix, chunk_comp, out);
}